// Round 13
// baseline (300.109 us; speedup 1.0000x reference)
//
#include <hip/hip_runtime.h>
#include <cstdint>

#define BB 2
#define NN 2048
#define DD 1024
#define HH 16
#define HD 64
#define HID_ 4096
#define MM (BB*NN)

typedef __bf16 bf16x8 __attribute__((ext_vector_type(8)));
typedef __bf16 bf16x4 __attribute__((ext_vector_type(4)));
typedef float  f32x4  __attribute__((ext_vector_type(4)));
typedef float  f32x2  __attribute__((ext_vector_type(2)));

__device__ inline void gload_lds16(const void* g, void* l) {
  __builtin_amdgcn_global_load_lds((const __attribute__((address_space(1))) char*)g,
                                   (__attribute__((address_space(3))) char*)l, 16, 0, 0);
}

// ---------- prep: decomposition weights + qkv bias concat + out-tail ----------
__global__ void k_wcomb(const float* __restrict__ alpha, const float* __restrict__ dw7,
                        const float* __restrict__ dw25, const float* __restrict__ dw49,
                        float* __restrict__ wc,
                        const float* __restrict__ bq, const float* __restrict__ bk,
                        const float* __restrict__ bv, float* __restrict__ b3,
                        float* __restrict__ out) {
  int t = blockIdx.x;  // 0..48 decomp weights, 49 = bias concat + tail
  if (t == 49) {
    if (threadIdx.x == 0) out[(size_t)BB * NN * DD] = 0.f;  // scalar output 1
    for (int i = threadIdx.x; i < 3 * DD; i += blockDim.x) {
      const float* s = (i < DD) ? bq : (i < 2 * DD ? bk : bv);
      b3[i] = s[i & (DD - 1)];
    }
    return;
  }
  float a0 = alpha[0], a1 = alpha[1], a2 = alpha[2];
  float mx = fmaxf(a0, fmaxf(a1, a2));
  float e0 = __expf(a0 - mx), e1 = __expf(a1 - mx), e2 = __expf(a2 - mx);
  float inv = 1.f / (e0 + e1 + e2);
  float w0 = e0 * inv, w1 = e1 * inv, w2 = e2 * inv;
  for (int d = threadIdx.x; d < DD; d += blockDim.x) {
    float v = w2 * dw49[d * 49 + t];
    if (t >= 12 && t <= 36) v += w1 * dw25[d * 25 + (t - 12)];
    if (t >= 21 && t <= 27) v += w0 * dw7[d * 7 + (t - 21)];
    wc[t * DD + d] = v;
  }
}

// weight converts + pbt transform in ONE launch.
__global__ __launch_bounds__(256) void k_cvtall(const float* __restrict__ Wq, const float* __restrict__ Wk,
                         const float* __restrict__ Wv, const float* __restrict__ Wo,
                         const float* __restrict__ W1, const float* __restrict__ W2,
                         const float* __restrict__ pb,
                         __bf16* __restrict__ dst, __bf16* __restrict__ pbt) {
  int bid = blockIdx.x;
  if (bid >= 12288) {
    int q = bid - 12288;
    int qt16 = q >> 4, qm = q & 15;
    const float LOG2E = 1.4426950408889634f;
    for (int k4 = threadIdx.x; k4 < NN / 4; k4 += 256) {
      int k = k4 * 4;
      float4 v = *(const float4*)&pb[(size_t)q * NN + k];
      int kt = k >> 4, g = (k >> 2) & 3;
      bf16x4 o;
      o[0] = (__bf16)(v.x * LOG2E); o[1] = (__bf16)(v.y * LOG2E);
      o[2] = (__bf16)(v.z * LOG2E); o[3] = (__bf16)(v.w * LOG2E);
      *(bf16x4*)&pbt[((size_t)qt16 * 128 + kt) * 256 + (qm + 16 * g) * 4] = o;
    }
    return;
  }
  size_t i = ((size_t)bid * 256 + threadIdx.x) * 4;
  const float* s;
  if (i < 1048576u) s = Wq + i;
  else if (i < 2097152u) s = Wk + (i - 1048576u);
  else if (i < 3145728u) s = Wv + (i - 2097152u);
  else if (i < 4194304u) s = Wo + (i - 3145728u);
  else if (i < 8388608u) s = W1 + (i - 4194304u);
  else s = W2 + (i - 8388608u);
  float4 v = *(const float4*)s;
  dst[i] = (__bf16)v.x; dst[i+1] = (__bf16)v.y; dst[i+2] = (__bf16)v.z; dst[i+3] = (__bf16)v.w;
}

// ---------- fused series decomposition + trend conv (bf16 outputs) ----------
__global__ __launch_bounds__(256) void k_decomp(const float* __restrict__ x,
                                                const float* __restrict__ wc,
                                                const float* __restrict__ tw,
                                                const float* __restrict__ tb,
                                                __bf16* __restrict__ S,
                                                __bf16* __restrict__ tout) {
  int bid = blockIdx.x;
  int db = bid & 3, ns = (bid >> 2) & 127, b = bid >> 9;
  int d = db * 256 + threadIdx.x;
  int n0 = ns * 16;
  const float* xb = x + (size_t)b * NN * DD + d;
  float xw[68];
#pragma unroll
  for (int i = 0; i < 68; ++i) {
    int n = n0 - 26 + i;
    n = (n < 0) ? -n : n;
    n = (n > NN - 1) ? 2 * (NN - 1) - n : n;
    xw[i] = xb[(size_t)n * DD];
  }
  float Tx[20];
#pragma unroll
  for (int j = 0; j < 20; ++j) Tx[j] = 0.f;
#pragma unroll
  for (int t = 0; t < 49; ++t) {
    float wv = wc[t * DD + d];
#pragma unroll
    for (int j = 0; j < 20; ++j) Tx[j] = fmaf(wv, xw[j + t], Tx[j]);
  }
#pragma unroll
  for (int j = 0; j < 20; ++j) {
    int row = n0 - 2 + j;
    if (row < 0 || row >= NN) Tx[j] = 0.f;
  }
  float tw5[5];
#pragma unroll
  for (int t = 0; t < 5; ++t) tw5[t] = tw[d * 5 + t];
  float tbv = tb[d];
  size_t base = ((size_t)b * NN + n0) * DD + d;
#pragma unroll
  for (int i = 0; i < 16; ++i) {
    S[base + (size_t)i * DD] = (__bf16)(xw[i + 26] - Tx[i + 2]);
    float acc = tbv;
#pragma unroll
    for (int t = 0; t < 5; ++t) acc = fmaf(tw5[t], Tx[i + t], acc);
    tout[base + (size_t)i * DD] = (__bf16)acc;
  }
}

// ---------- LayerNorm (bf16 in -> bf16 out) ----------
__global__ __launch_bounds__(256) void k_ln(const __bf16* __restrict__ xv,
                                            const float* __restrict__ g,
                                            const float* __restrict__ bt,
                                            __bf16* __restrict__ y) {
  int row = blockIdx.x;
  int i = threadIdx.x * 4;
  bf16x4 x4 = *(const bf16x4*)(xv + (size_t)row * DD + i);
  float4 v;
  v.x = (float)x4[0]; v.y = (float)x4[1]; v.z = (float)x4[2]; v.w = (float)x4[3];
  float s = v.x + v.y + v.z + v.w;
  float sq = v.x * v.x + v.y * v.y + v.z * v.z + v.w * v.w;
#pragma unroll
  for (int m = 1; m <= 32; m <<= 1) { s += __shfl_xor(s, m); sq += __shfl_xor(sq, m); }
  __shared__ float rs[4], rq[4];
  int wid = threadIdx.x >> 6;
  if ((threadIdx.x & 63) == 0) { rs[wid] = s; rq[wid] = sq; }
  __syncthreads();
  s = rs[0] + rs[1] + rs[2] + rs[3];
  sq = rq[0] + rq[1] + rq[2] + rq[3];
  float mean = s * (1.f / DD);
  float var = sq * (1.f / DD) - mean * mean;
  float rstd = rsqrtf(var + 1e-5f);
  float4 gv = *(const float4*)&g[i];
  float4 bv = *(const float4*)&bt[i];
  __bf16* yr = y + (size_t)row * DD + i;
  yr[0] = (__bf16)((v.x - mean) * rstd * gv.x + bv.x);
  yr[1] = (__bf16)((v.y - mean) * rstd * gv.y + bv.y);
  yr[2] = (__bf16)((v.z - mean) * rstd * gv.z + bv.z);
  yr[3] = (__bf16)((v.w - mean) * rstd * gv.w + bv.w);
}

// ---------- GEMM: C[M,N] = A[M,K] * Bw[N,K]^T, tile 128 x BNT, K-step BKT ----------
template <int EPI, int BNT, int BKT>
__global__ __launch_bounds__(256) void k_gemm(const __bf16* __restrict__ A,
                                              const __bf16* __restrict__ Bw, int K,
                                              const float* __restrict__ bias,
                                              const __bf16* __restrict__ auxb1,
                                              const __bf16* __restrict__ auxb2,
                                              float* __restrict__ outf,
                                              __bf16* __restrict__ outb) {
  constexpr int NFR = BNT / 32;
  constexpr int NKK = BKT / 32;
  __shared__ __bf16 aS[2][128 * BKT];
  __shared__ __bf16 bS[2][BNT * BKT];
  const int tid = threadIdx.x;
  const int lane = tid & 63;
  const int wid = tid >> 6;
  const int wm = wid >> 1, wn = wid & 1;
  const int r = lane & 15, gq = lane >> 4;
  const int gx = gridDim.x;
  const int G = gx * gridDim.y;
  int bid = blockIdx.y * gx + blockIdx.x;
  int swz = (bid & 7) * (G >> 3) + (bid >> 3);
  const int m0 = (swz / gx) * 128;
  const int n0 = (swz % gx) * BNT;
  const int rsw = (BKT == 64) ? (r & 7) * 8 : 0;

  f32x4 acc[4][NFR];
#pragma unroll
  for (int mi = 0; mi < 4; ++mi)
#pragma unroll
    for (int ni = 0; ni < NFR; ++ni) acc[mi][ni] = (f32x4){0.f, 0.f, 0.f, 0.f};

  auto stage = [&](int bufi, int k0) {
#pragma unroll
    for (int i = 0; i < (128 * BKT) / 2048; ++i) {
      int e = i * 2048 + tid * 8;
      int row = e / BKT, col = e % BKT;
      int src = (BKT == 64) ? (col ^ ((row & 7) * 8)) : col;
      gload_lds16(A + (size_t)(m0 + row) * K + k0 + src, &aS[bufi][e]);
    }
#pragma unroll
    for (int i = 0; i < (BNT * BKT) / 2048; ++i) {
      int e = i * 2048 + tid * 8;
      int row = e / BKT, col = e % BKT;
      int src = (BKT == 64) ? (col ^ ((row & 7) * 8)) : col;
      gload_lds16(Bw + (size_t)(n0 + row) * K + k0 + src, &bS[bufi][e]);
    }
  };

  stage(0, 0);
  const int nk = K / BKT;
  int buf = 0;
  for (int kt = 0; kt < nk; ++kt) {
    __syncthreads();
    if (kt + 1 < nk) stage(buf ^ 1, (kt + 1) * BKT);
    bf16x8 af[4][NKK], bfr[NFR][NKK];
#pragma unroll
    for (int mi = 0; mi < 4; ++mi)
#pragma unroll
      for (int kk = 0; kk < NKK; ++kk)
        af[mi][kk] = *reinterpret_cast<const bf16x8*>(
            &aS[buf][(wm * 64 + mi * 16 + r) * BKT + ((kk * 32 + gq * 8) ^ rsw)]);
#pragma unroll
    for (int ni = 0; ni < NFR; ++ni)
#pragma unroll
      for (int kk = 0; kk < NKK; ++kk)
        bfr[ni][kk] = *reinterpret_cast<const bf16x8*>(
            &bS[buf][(wn * (BNT / 2) + ni * 16 + r) * BKT + ((kk * 32 + gq * 8) ^ rsw)]);
    __builtin_amdgcn_s_setprio(1);
#pragma unroll
    for (int kk = 0; kk < NKK; ++kk)
#pragma unroll
      for (int mi = 0; mi < 4; ++mi)
#pragma unroll
        for (int ni = 0; ni < NFR; ++ni)
          acc[mi][ni] = __builtin_amdgcn_mfma_f32_16x16x32_bf16(af[mi][kk], bfr[ni][kk], acc[mi][ni], 0, 0, 0);
    __builtin_amdgcn_s_setprio(0);
    buf ^= 1;
  }

#pragma unroll
  for (int mi = 0; mi < 4; ++mi) {
#pragma unroll
    for (int ni = 0; ni < NFR; ++ni) {
      int colg = n0 + wn * (BNT / 2) + ni * 16 + r;
      float bcol = bias[colg];
#pragma unroll
      for (int rr = 0; rr < 4; ++rr) {
        int mg = m0 + wm * 64 + mi * 16 + gq * 4 + rr;
        float val = acc[mi][ni][rr] + bcol;
        if constexpr (EPI == 0) {
          int which = colg >> 10, e = colg & 1023;
          int hh = e >> 6, d = e & 63;
          int b = mg >> 11, nq = mg & (NN - 1);
          if (which == 2) {
            int nl = nq & 63, kk = nl & 31;
            int slot = ((kk >> 4) << 2) | (((kk >> 2) & 3) << 3) | (kk & 3) | (nl & 32);
            int nqp = (nq & ~63) | slot;
            outb[(size_t)2 * (BB * HH * NN * HD) +
                 ((size_t)((b * HH + hh) * HD + d)) * NN + nqp] = (__bf16)val;
          } else {
            outb[(size_t)which * (BB * HH * NN * HD) +
                 ((size_t)(b * HH + hh) * NN + nq) * HD + d] = (__bf16)val;
          }
        } else if constexpr (EPI == 1) {
          size_t idx = (size_t)mg * DD + colg;
          outb[idx] = (__bf16)((float)auxb1[idx] + val);
        } else if constexpr (EPI == 2) {
          float gl = val * 0.5f * (1.f + erff(val * 0.70710678118f));
          outb[(size_t)mg * HID_ + colg] = (__bf16)gl;
        } else {
          size_t idx = (size_t)mg * DD + colg;
          outf[idx] = val + (float)auxb1[idx] + (float)auxb2[idx];
        }
      }
    }
  }
}

// ---------- flash attention: no online max + ALiBi chunk truncation ----------
// ALiBi: future chunks past D = 64/ls tokens beyond the block's last q-row
// contribute < 2^-39 each relative to guaranteed-kept diagonal terms (< 2^-28
// summed) -> stop the chunk loop early. Block-uniform bound, no divergence.
__global__ __launch_bounds__(512) void k_attn(const __bf16* __restrict__ qb,
                                              const __bf16* __restrict__ kb,
                                              const __bf16* __restrict__ vtb,
                                              const __bf16* __restrict__ pbt,
                                              __bf16* __restrict__ ob) {
  __shared__ __bf16 kS[2][64 * 64];
  __shared__ __bf16 vS[2][64 * 64];
  int blk = ((blockIdx.x & 7) << 6) | (blockIdx.x >> 3);
  int qt = blk & 15, bh = blk >> 4;
  int h = bh & (HH - 1), b = bh >> 4;
  int tid = threadIdx.x;
  int lane = tid & 63, w = tid >> 6;
  int r = lane & 15, g = lane >> 4;
  const __bf16* Kp = kb + (size_t)bh * NN * HD;
  const __bf16* Vt = vtb + (size_t)bh * HD * NN;
  int qbase = qt * 128 + w * 16;
  int cq = qt * 2 + (w >> 2);
  const __bf16* Q = qb + ((size_t)bh * NN + qbase) * HD;

  bf16x8 qf0 = *(const bf16x8*)&Q[(size_t)r * HD + g * 8];
  bf16x8 qf1 = *(const bf16x8*)&Q[(size_t)r * HD + 32 + g * 8];
  bf16x8 onesf;
#pragma unroll
  for (int j = 0; j < 8; ++j) onesf[j] = (__bf16)1.0f;

  const float C = 0.18033688011112042f;          // 0.125 * log2(e)
  const f32x2 C2 = {C, C};
  float slope = exp2f(-0.5f * (float)(h + 1)) * 1.4426950408889634f;  // log2/token
  f32x2 sconst2[8];
#pragma unroll
  for (int st = 0; st < 4; ++st) {
    sconst2[st * 2]     = (f32x2){slope * (float)(st * 16),     slope * (float)(st * 16 + 1)};
    sconst2[st * 2 + 1] = (f32x2){slope * (float)(st * 16 + 2), slope * (float)(st * 16 + 3)};
  }
  float aL = slope * (float)(g * 4 - r);

  // truncation: last chunk with any token within 64 log2-units of suppression
  int qmaxb = qt * 128 + 127;
  int lastch = (int)floorf(((float)qmaxb + 64.0f / slope) * (1.0f / 64.0f));
  int nch = min(NN / 64, lastch + 1);   // nch >= 2*qt+2 > cq always

  f32x4 oacc[4], lacc;
#pragma unroll
  for (int t = 0; t < 4; ++t) oacc[t] = (f32x4){0.f, 0.f, 0.f, 0.f};
  lacc = (f32x4){0.f, 0.f, 0.f, 0.f};

  auto stage = [&](int bufi, int kc0) {
    int row = tid >> 3;
    int c = (tid & 7) * 8;
    int src = c ^ ((row & 7) * 8);
    gload_lds16(Kp + (size_t)(kc0 + row) * HD + src, &kS[bufi][tid * 8]);
    gload_lds16(Vt + (size_t)row * NN + kc0 + src, &vS[bufi][tid * 8]);
  };

  stage(0, 0);
  int buf = 0;
  size_t tilebase = (size_t)(qt * 8 + w) * 128;
  int sw = (r & 7) * 8;

  for (int ch = 0; ch < nch; ++ch) {
    int kc0 = ch * 64;
    __syncthreads();
    if (ch + 1 < nch) stage(buf ^ 1, kc0 + 64);

    uint2 ub[4];
#pragma unroll
    for (int st = 0; st < 4; ++st)
      ub[st] = *(const uint2*)&pbt[(tilebase + (kc0 >> 4) + st) * 256 + lane * 4];

    f32x4 sacc[4];
    __builtin_amdgcn_s_setprio(1);
#pragma unroll
    for (int st = 0; st < 4; ++st) {
      sacc[st] = (f32x4){0.f, 0.f, 0.f, 0.f};
      int rowb = (st * 16 + r) * 64;
      bf16x8 kf0 = *(const bf16x8*)&kS[buf][rowb + ((g * 8) ^ sw)];
      bf16x8 kf1 = *(const bf16x8*)&kS[buf][rowb + ((32 + g * 8) ^ sw)];
      sacc[st] = __builtin_amdgcn_mfma_f32_16x16x32_bf16(kf0, qf0, sacc[st], 0, 0, 0);
      sacc[st] = __builtin_amdgcn_mfma_f32_16x16x32_bf16(kf1, qf1, sacc[st], 0, 0, 0);
    }
    __builtin_amdgcn_s_setprio(0);

    // z = logit (log2 domain), packed pairs; no running max needed
    f32x2 z2[8];
    if (ch > cq) {
      float uu = fmaf(slope, (float)(kc0 - qbase), aL);
      f32x2 uu2 = {uu, uu};
#pragma unroll
      for (int st = 0; st < 4; ++st) {
        f32x2 pbl = {__uint_as_float(ub[st].x << 16), __uint_as_float(ub[st].x & 0xffff0000u)};
        f32x2 pbh = {__uint_as_float(ub[st].y << 16), __uint_as_float(ub[st].y & 0xffff0000u)};
        f32x2 s0 = {sacc[st][0], sacc[st][1]};
        f32x2 s1 = {sacc[st][2], sacc[st][3]};
        z2[st*2]   = s0 * C2 + pbl - (uu2 + sconst2[st*2]);
        z2[st*2+1] = s1 * C2 + pbh - (uu2 + sconst2[st*2+1]);
      }
    } else if (ch < cq) {
#pragma unroll
      for (int st = 0; st < 4; ++st) {
        f32x2 pbl = {__uint_as_float(ub[st].x << 16), __uint_as_float(ub[st].x & 0xffff0000u)};
        f32x2 pbh = {__uint_as_float(ub[st].y << 16), __uint_as_float(ub[st].y & 0xffff0000u)};
        f32x2 s0 = {sacc[st][0], sacc[st][1]};
        f32x2 s1 = {sacc[st][2], sacc[st][3]};
        z2[st*2]   = s0 * C2 + pbl;
        z2[st*2+1] = s1 * C2 + pbh;
      }
    } else {
      int kqb = kc0 + g * 4 - qbase - r;
#pragma unroll
      for (int st = 0; st < 4; ++st) {
        float p0 = __uint_as_float(ub[st].x << 16);
        float p1 = __uint_as_float(ub[st].x & 0xffff0000u);
        float p2 = __uint_as_float(ub[st].y << 16);
        float p3 = __uint_as_float(ub[st].y & 0xffff0000u);
        float pb4[4] = {p0, p1, p2, p3};
#pragma unroll
        for (int rr = 0; rr < 4; ++rr) {
          int dk = kqb + st * 16 + rr;
          float dist = (dk > 0) ? (float)dk : 0.f;
          z2[st*2 + (rr >> 1)][rr & 1] = fmaf(sacc[st][rr], C, pb4[rr]) - slope * dist;
        }
      }
    }

    // exp2 + pack straight into PV A-fragments (k-perm matches V's sigma layout)
    bf16x8 pa0, pa1;
#pragma unroll
    for (int j = 0; j < 8; ++j) {
      pa0[j] = (__bf16)exp2f(z2[j >> 1][j & 1]);
      pa1[j] = (__bf16)exp2f(z2[4 + (j >> 1)][j & 1]);
    }

    __builtin_amdgcn_s_setprio(1);
#pragma unroll
    for (int t = 0; t < 4; ++t) {
      int rowb = (t * 16 + r) * 64;
      bf16x8 vf0 = *(const bf16x8*)&vS[buf][rowb + ((g * 8) ^ sw)];
      bf16x8 vf1 = *(const bf16x8*)&vS[buf][rowb + ((32 + g * 8) ^ sw)];
      oacc[t] = __builtin_amdgcn_mfma_f32_16x16x32_bf16(pa0, vf0, oacc[t], 0, 0, 0);
      oacc[t] = __builtin_amdgcn_mfma_f32_16x16x32_bf16(pa1, vf1, oacc[t], 0, 0, 0);
    }
    lacc = __builtin_amdgcn_mfma_f32_16x16x32_bf16(pa0, onesf, lacc, 0, 0, 0);
    lacc = __builtin_amdgcn_mfma_f32_16x16x32_bf16(pa1, onesf, lacc, 0, 0, 0);
    __builtin_amdgcn_s_setprio(0);
    buf ^= 1;
  }

#pragma unroll
  for (int rr = 0; rr < 4; ++rr) {
    int qg = qbase + g * 4 + rr;
    float inv = 1.f / lacc[rr];
#pragma unroll
    for (int t = 0; t < 4; ++t) {
      float v = oacc[t][rr] * inv;
      ob[((size_t)(b * NN) + qg) * DD + h * HD + t * 16 + r] = (__bf16)v;
    }
  }
}

extern "C" void kernel_launch(void* const* d_in, const int* in_sizes, int n_in,
                              void* d_out, int out_size, void* d_ws, size_t ws_size,
                              hipStream_t stream) {
  const float* x    = (const float*)d_in[0];
  const float* pb   = (const float*)d_in[1];
  const float* alpha= (const float*)d_in[2];
  const float* dw7  = (const float*)d_in[3];
  const float* dw25 = (const float*)d_in[4];
  const float* dw49 = (const float*)d_in[5];
  const float* ln1g = (const float*)d_in[6];
  const float* ln1b = (const float*)d_in[7];
  const float* ln2g = (const float*)d_in[8];
  const float* ln2b = (const float*)d_in[9];
  const float* Wq   = (const float*)d_in[10];
  const float* bq   = (const float*)d_in[11];
  const float* Wk   = (const float*)d_in[12];
  const float* bk   = (const float*)d_in[13];
  const float* Wv   = (const float*)d_in[14];
  const float* bv   = (const float*)d_in[15];
  const float* Wo   = (const float*)d_in[16];
  const float* bo   = (const float*)d_in[17];
  const float* W1   = (const float*)d_in[18];
  const float* b1   = (const float*)d_in[19];
  const float* W2   = (const float*)d_in[20];
  const float* b2   = (const float*)d_in[21];
  const float* tw   = (const float*)d_in[22];
  const float* tb   = (const float*)d_in[23];
  float* out = (float*)d_out;

  char* w = (char*)d_ws;
  size_t off = 0;
  auto alloc = [&](size_t bytes) -> char* {
    char* p = w + off;
    off = (off + bytes + 255) & ~(size_t)255;
    return p;
  };
  float*  wc    = (float*)alloc(49 * 1024 * 4);
  float*  b3    = (float*)alloc(3072 * 4);
  __bf16* xs    = (__bf16*)alloc((size_t)MM * DD * 2);
  __bf16* Sb    = (__bf16*)alloc((size_t)MM * DD * 2);
  __bf16* toutb = (__bf16*)alloc((size_t)MM * DD * 2);
  __bf16* sn    = (__bf16*)alloc((size_t)MM * DD * 2);
  __bf16* qkv   = (__bf16*)alloc((size_t)3 * MM * DD * 2);
  __bf16* gb    = (__bf16*)alloc((size_t)MM * HID_ * 2);
  __bf16* wall  = (__bf16*)alloc((size_t)12582912 * 2);
  __bf16* pbt   = (__bf16*)alloc((size_t)NN * NN * 2);
  __bf16* wqkvb = wall;
  __bf16* wob   = wall + (size_t)3 * DD * DD;
  __bf16* w1b   = wall + (size_t)4 * DD * DD;
  __bf16* w2b   = wall + (size_t)4 * DD * DD + (size_t)HID_ * DD;
  __bf16* obuf  = sn;     // alias: sn dead after QKV gemm
  __bf16* hb    = qkv;    // alias: q dead after attention

  const size_t BHND = (size_t)BB * HH * NN * HD;

  k_wcomb<<<50, 256, 0, stream>>>(alpha, dw7, dw25, dw49, wc, bq, bk, bv, b3, out);
  k_cvtall<<<14336, 256, 0, stream>>>(Wq, Wk, Wv, Wo, W1, W2, pb, wall, pbt);
  k_decomp<<<1024, 256, 0, stream>>>(x, wc, tw, tb, Sb, toutb);
  k_ln<<<MM, 256, 0, stream>>>(Sb, ln1g, ln1b, sn);
  k_gemm<0,128,32><<<dim3(24, 32), 256, 0, stream>>>(sn, wqkvb, DD, b3, nullptr, nullptr, nullptr, qkv);
  k_attn<<<BB * HH * (NN / 128), 512, 0, stream>>>(qkv, qkv + BHND, qkv + 2 * BHND, pbt, obuf);
  k_gemm<1,64,64><<<dim3(16, 32), 256, 0, stream>>>(obuf, wob, DD, bo, Sb, nullptr, nullptr, xs);
  k_ln<<<MM, 256, 0, stream>>>(xs, ln2g, ln2b, hb);
  k_gemm<2,128,64><<<dim3(32, 32), 256, 0, stream>>>(hb, w1b, DD, b1, nullptr, nullptr, nullptr, gb);
  k_gemm<3,64,64><<<dim3(16, 32), 256, 0, stream>>>(gb, w2b, HID_, b2, xs, toutb, out, nullptr);
}

// Round 14
// 298.921 us; speedup vs baseline: 1.0040x; 1.0040x over previous
//
#include <hip/hip_runtime.h>
#include <cstdint>

#define BB 2
#define NN 2048
#define DD 1024
#define HH 16
#define HD 64
#define HID_ 4096
#define MM (BB*NN)

typedef __bf16 bf16x8 __attribute__((ext_vector_type(8)));
typedef __bf16 bf16x4 __attribute__((ext_vector_type(4)));
typedef float  f32x4  __attribute__((ext_vector_type(4)));
typedef float  f32x2  __attribute__((ext_vector_type(2)));

__device__ inline void gload_lds16(const void* g, void* l) {
  __builtin_amdgcn_global_load_lds((const __attribute__((address_space(1))) char*)g,
                                   (__attribute__((address_space(3))) char*)l, 16, 0, 0);
}

// ---------- prep: decomposition weights + qkv bias concat + out-tail ----------
__global__ void k_wcomb(const float* __restrict__ alpha, const float* __restrict__ dw7,
                        const float* __restrict__ dw25, const float* __restrict__ dw49,
                        float* __restrict__ wc,
                        const float* __restrict__ bq, const float* __restrict__ bk,
                        const float* __restrict__ bv, float* __restrict__ b3,
                        float* __restrict__ out) {
  int t = blockIdx.x;  // 0..48 decomp weights, 49 = bias concat + tail
  if (t == 49) {
    if (threadIdx.x == 0) out[(size_t)BB * NN * DD] = 0.f;  // scalar output 1
    for (int i = threadIdx.x; i < 3 * DD; i += blockDim.x) {
      const float* s = (i < DD) ? bq : (i < 2 * DD ? bk : bv);
      b3[i] = s[i & (DD - 1)];
    }
    return;
  }
  float a0 = alpha[0], a1 = alpha[1], a2 = alpha[2];
  float mx = fmaxf(a0, fmaxf(a1, a2));
  float e0 = __expf(a0 - mx), e1 = __expf(a1 - mx), e2 = __expf(a2 - mx);
  float inv = 1.f / (e0 + e1 + e2);
  float w0 = e0 * inv, w1 = e1 * inv, w2 = e2 * inv;
  for (int d = threadIdx.x; d < DD; d += blockDim.x) {
    float v = w2 * dw49[d * 49 + t];
    if (t >= 12 && t <= 36) v += w1 * dw25[d * 25 + (t - 12)];
    if (t >= 21 && t <= 27) v += w0 * dw7[d * 7 + (t - 21)];
    wc[t * DD + d] = v;
  }
}

// weight converts + pbt transform in ONE launch.
__global__ __launch_bounds__(256) void k_cvtall(const float* __restrict__ Wq, const float* __restrict__ Wk,
                         const float* __restrict__ Wv, const float* __restrict__ Wo,
                         const float* __restrict__ W1, const float* __restrict__ W2,
                         const float* __restrict__ pb,
                         __bf16* __restrict__ dst, __bf16* __restrict__ pbt) {
  int bid = blockIdx.x;
  if (bid >= 12288) {
    int q = bid - 12288;
    int qt16 = q >> 4, qm = q & 15;
    const float LOG2E = 1.4426950408889634f;
    for (int k4 = threadIdx.x; k4 < NN / 4; k4 += 256) {
      int k = k4 * 4;
      float4 v = *(const float4*)&pb[(size_t)q * NN + k];
      int kt = k >> 4, g = (k >> 2) & 3;
      bf16x4 o;
      o[0] = (__bf16)(v.x * LOG2E); o[1] = (__bf16)(v.y * LOG2E);
      o[2] = (__bf16)(v.z * LOG2E); o[3] = (__bf16)(v.w * LOG2E);
      *(bf16x4*)&pbt[((size_t)qt16 * 128 + kt) * 256 + (qm + 16 * g) * 4] = o;
    }
    return;
  }
  size_t i = ((size_t)bid * 256 + threadIdx.x) * 4;
  const float* s;
  if (i < 1048576u) s = Wq + i;
  else if (i < 2097152u) s = Wk + (i - 1048576u);
  else if (i < 3145728u) s = Wv + (i - 2097152u);
  else if (i < 4194304u) s = Wo + (i - 3145728u);
  else if (i < 8388608u) s = W1 + (i - 4194304u);
  else s = W2 + (i - 8388608u);
  float4 v = *(const float4*)s;
  dst[i] = (__bf16)v.x; dst[i+1] = (__bf16)v.y; dst[i+2] = (__bf16)v.z; dst[i+3] = (__bf16)v.w;
}

// ---------- fused series decomposition + trend conv (bf16 outputs) ----------
__global__ __launch_bounds__(256) void k_decomp(const float* __restrict__ x,
                                                const float* __restrict__ wc,
                                                const float* __restrict__ tw,
                                                const float* __restrict__ tb,
                                                __bf16* __restrict__ S,
                                                __bf16* __restrict__ tout) {
  int bid = blockIdx.x;
  int db = bid & 3, ns = (bid >> 2) & 127, b = bid >> 9;
  int d = db * 256 + threadIdx.x;
  int n0 = ns * 16;
  const float* xb = x + (size_t)b * NN * DD + d;
  float xw[68];
#pragma unroll
  for (int i = 0; i < 68; ++i) {
    int n = n0 - 26 + i;
    n = (n < 0) ? -n : n;
    n = (n > NN - 1) ? 2 * (NN - 1) - n : n;
    xw[i] = xb[(size_t)n * DD];
  }
  float Tx[20];
#pragma unroll
  for (int j = 0; j < 20; ++j) Tx[j] = 0.f;
#pragma unroll
  for (int t = 0; t < 49; ++t) {
    float wv = wc[t * DD + d];
#pragma unroll
    for (int j = 0; j < 20; ++j) Tx[j] = fmaf(wv, xw[j + t], Tx[j]);
  }
#pragma unroll
  for (int j = 0; j < 20; ++j) {
    int row = n0 - 2 + j;
    if (row < 0 || row >= NN) Tx[j] = 0.f;
  }
  float tw5[5];
#pragma unroll
  for (int t = 0; t < 5; ++t) tw5[t] = tw[d * 5 + t];
  float tbv = tb[d];
  size_t base = ((size_t)b * NN + n0) * DD + d;
#pragma unroll
  for (int i = 0; i < 16; ++i) {
    S[base + (size_t)i * DD] = (__bf16)(xw[i + 26] - Tx[i + 2]);
    float acc = tbv;
#pragma unroll
    for (int t = 0; t < 5; ++t) acc = fmaf(tw5[t], Tx[i + t], acc);
    tout[base + (size_t)i * DD] = (__bf16)acc;
  }
}

// ---------- LayerNorm (bf16 in -> bf16 out) ----------
__global__ __launch_bounds__(256) void k_ln(const __bf16* __restrict__ xv,
                                            const float* __restrict__ g,
                                            const float* __restrict__ bt,
                                            __bf16* __restrict__ y) {
  int row = blockIdx.x;
  int i = threadIdx.x * 4;
  bf16x4 x4 = *(const bf16x4*)(xv + (size_t)row * DD + i);
  float4 v;
  v.x = (float)x4[0]; v.y = (float)x4[1]; v.z = (float)x4[2]; v.w = (float)x4[3];
  float s = v.x + v.y + v.z + v.w;
  float sq = v.x * v.x + v.y * v.y + v.z * v.z + v.w * v.w;
#pragma unroll
  for (int m = 1; m <= 32; m <<= 1) { s += __shfl_xor(s, m); sq += __shfl_xor(sq, m); }
  __shared__ float rs[4], rq[4];
  int wid = threadIdx.x >> 6;
  if ((threadIdx.x & 63) == 0) { rs[wid] = s; rq[wid] = sq; }
  __syncthreads();
  s = rs[0] + rs[1] + rs[2] + rs[3];
  sq = rq[0] + rq[1] + rq[2] + rq[3];
  float mean = s * (1.f / DD);
  float var = sq * (1.f / DD) - mean * mean;
  float rstd = rsqrtf(var + 1e-5f);
  float4 gv = *(const float4*)&g[i];
  float4 bv = *(const float4*)&bt[i];
  __bf16* yr = y + (size_t)row * DD + i;
  yr[0] = (__bf16)((v.x - mean) * rstd * gv.x + bv.x);
  yr[1] = (__bf16)((v.y - mean) * rstd * gv.y + bv.y);
  yr[2] = (__bf16)((v.z - mean) * rstd * gv.z + bv.z);
  yr[3] = (__bf16)((v.w - mean) * rstd * gv.w + bv.w);
}

// ---------- GEMM: C[M,N] = A[M,K] * Bw[N,K]^T, tile 128 x BNT, K-step BKT ----------
template <int EPI, int BNT, int BKT>
__global__ __launch_bounds__(256) void k_gemm(const __bf16* __restrict__ A,
                                              const __bf16* __restrict__ Bw, int K,
                                              const float* __restrict__ bias,
                                              const __bf16* __restrict__ auxb1,
                                              const __bf16* __restrict__ auxb2,
                                              float* __restrict__ outf,
                                              __bf16* __restrict__ outb) {
  constexpr int NFR = BNT / 32;
  constexpr int NKK = BKT / 32;
  __shared__ __bf16 aS[2][128 * BKT];
  __shared__ __bf16 bS[2][BNT * BKT];
  const int tid = threadIdx.x;
  const int lane = tid & 63;
  const int wid = tid >> 6;
  const int wm = wid >> 1, wn = wid & 1;
  const int r = lane & 15, gq = lane >> 4;
  const int gx = gridDim.x;
  const int G = gx * gridDim.y;
  int bid = blockIdx.y * gx + blockIdx.x;
  int swz = (bid & 7) * (G >> 3) + (bid >> 3);
  const int m0 = (swz / gx) * 128;
  const int n0 = (swz % gx) * BNT;
  const int rsw = (BKT == 64) ? (r & 7) * 8 : 0;

  f32x4 acc[4][NFR];
#pragma unroll
  for (int mi = 0; mi < 4; ++mi)
#pragma unroll
    for (int ni = 0; ni < NFR; ++ni) acc[mi][ni] = (f32x4){0.f, 0.f, 0.f, 0.f};

  auto stage = [&](int bufi, int k0) {
#pragma unroll
    for (int i = 0; i < (128 * BKT) / 2048; ++i) {
      int e = i * 2048 + tid * 8;
      int row = e / BKT, col = e % BKT;
      int src = (BKT == 64) ? (col ^ ((row & 7) * 8)) : col;
      gload_lds16(A + (size_t)(m0 + row) * K + k0 + src, &aS[bufi][e]);
    }
#pragma unroll
    for (int i = 0; i < (BNT * BKT) / 2048; ++i) {
      int e = i * 2048 + tid * 8;
      int row = e / BKT, col = e % BKT;
      int src = (BKT == 64) ? (col ^ ((row & 7) * 8)) : col;
      gload_lds16(Bw + (size_t)(n0 + row) * K + k0 + src, &bS[bufi][e]);
    }
  };

  stage(0, 0);
  const int nk = K / BKT;
  int buf = 0;
  for (int kt = 0; kt < nk; ++kt) {
    __syncthreads();
    if (kt + 1 < nk) stage(buf ^ 1, (kt + 1) * BKT);
    bf16x8 af[4][NKK], bfr[NFR][NKK];
#pragma unroll
    for (int mi = 0; mi < 4; ++mi)
#pragma unroll
      for (int kk = 0; kk < NKK; ++kk)
        af[mi][kk] = *reinterpret_cast<const bf16x8*>(
            &aS[buf][(wm * 64 + mi * 16 + r) * BKT + ((kk * 32 + gq * 8) ^ rsw)]);
#pragma unroll
    for (int ni = 0; ni < NFR; ++ni)
#pragma unroll
      for (int kk = 0; kk < NKK; ++kk)
        bfr[ni][kk] = *reinterpret_cast<const bf16x8*>(
            &bS[buf][(wn * (BNT / 2) + ni * 16 + r) * BKT + ((kk * 32 + gq * 8) ^ rsw)]);
    __builtin_amdgcn_s_setprio(1);
#pragma unroll
    for (int kk = 0; kk < NKK; ++kk)
#pragma unroll
      for (int mi = 0; mi < 4; ++mi)
#pragma unroll
        for (int ni = 0; ni < NFR; ++ni)
          acc[mi][ni] = __builtin_amdgcn_mfma_f32_16x16x32_bf16(af[mi][kk], bfr[ni][kk], acc[mi][ni], 0, 0, 0);
    __builtin_amdgcn_s_setprio(0);
    buf ^= 1;
  }

#pragma unroll
  for (int mi = 0; mi < 4; ++mi) {
#pragma unroll
    for (int ni = 0; ni < NFR; ++ni) {
      int colg = n0 + wn * (BNT / 2) + ni * 16 + r;
      float bcol = bias[colg];
#pragma unroll
      for (int rr = 0; rr < 4; ++rr) {
        int mg = m0 + wm * 64 + mi * 16 + gq * 4 + rr;
        float val = acc[mi][ni][rr] + bcol;
        if constexpr (EPI == 0) {
          int which = colg >> 10, e = colg & 1023;
          int hh = e >> 6, d = e & 63;
          int b = mg >> 11, nq = mg & (NN - 1);
          if (which == 2) {
            int nl = nq & 63, kk = nl & 31;
            int slot = ((kk >> 4) << 2) | (((kk >> 2) & 3) << 3) | (kk & 3) | (nl & 32);
            int nqp = (nq & ~63) | slot;
            outb[(size_t)2 * (BB * HH * NN * HD) +
                 ((size_t)((b * HH + hh) * HD + d)) * NN + nqp] = (__bf16)val;
          } else {
            outb[(size_t)which * (BB * HH * NN * HD) +
                 ((size_t)(b * HH + hh) * NN + nq) * HD + d] = (__bf16)val;
          }
        } else if constexpr (EPI == 1) {
          size_t idx = (size_t)mg * DD + colg;
          outb[idx] = (__bf16)((float)auxb1[idx] + val);
        } else if constexpr (EPI == 2) {
          float gl = val * 0.5f * (1.f + erff(val * 0.70710678118f));
          outb[(size_t)mg * HID_ + colg] = (__bf16)gl;
        } else {
          size_t idx = (size_t)mg * DD + colg;
          outf[idx] = val + (float)auxb1[idx] + (float)auxb2[idx];
        }
      }
    }
  }
}

// ---------- flash attention: truncated chunks + LPT (longest-first) dispatch ----------
// Work per block ~ nch(h,qt); h=15 does all 32 chunks, h=0 ~ 18 avg. Dispatch
// h-descending so long blocks start first and short ones backfill (LPT).
// Within an h-group, XCD x takes b=x&1 and 4 consecutive qt (partial L2 reuse).
__global__ __launch_bounds__(512) void k_attn(const __bf16* __restrict__ qb,
                                              const __bf16* __restrict__ kb,
                                              const __bf16* __restrict__ vtb,
                                              const __bf16* __restrict__ pbt,
                                              __bf16* __restrict__ ob) {
  __shared__ __bf16 kS[2][64 * 64];
  __shared__ __bf16 vS[2][64 * 64];
  int i = blockIdx.x;
  int x = i & 7;                 // XCD (round-robin on dispatch index)
  int t0 = i >> 3;               // 0..63
  int h = 15 - (t0 >> 2);        // h-group, descending work
  int u = t0 & 3;
  int b = x & 1;
  int qt = (x >> 1) * 4 + u;
  int bh = b * HH + h;
  int tid = threadIdx.x;
  int lane = tid & 63, w = tid >> 6;
  int r = lane & 15, g = lane >> 4;
  const __bf16* Kp = kb + (size_t)bh * NN * HD;
  const __bf16* Vt = vtb + (size_t)bh * HD * NN;
  int qbase = qt * 128 + w * 16;
  int cq = qt * 2 + (w >> 2);
  const __bf16* Q = qb + ((size_t)bh * NN + qbase) * HD;

  bf16x8 qf0 = *(const bf16x8*)&Q[(size_t)r * HD + g * 8];
  bf16x8 qf1 = *(const bf16x8*)&Q[(size_t)r * HD + 32 + g * 8];
  bf16x8 onesf;
#pragma unroll
  for (int j = 0; j < 8; ++j) onesf[j] = (__bf16)1.0f;

  const float C = 0.18033688011112042f;          // 0.125 * log2(e)
  const f32x2 C2 = {C, C};
  float slope = exp2f(-0.5f * (float)(h + 1)) * 1.4426950408889634f;  // log2/token
  f32x2 sconst2[8];
#pragma unroll
  for (int st = 0; st < 4; ++st) {
    sconst2[st * 2]     = (f32x2){slope * (float)(st * 16),     slope * (float)(st * 16 + 1)};
    sconst2[st * 2 + 1] = (f32x2){slope * (float)(st * 16 + 2), slope * (float)(st * 16 + 3)};
  }
  float aL = slope * (float)(g * 4 - r);

  // truncation: last chunk with any token within 64 log2-units of suppression
  int qmaxb = qt * 128 + 127;
  int lastch = (int)floorf(((float)qmaxb + 64.0f / slope) * (1.0f / 64.0f));
  int nch = min(NN / 64, lastch + 1);   // nch >= 2*qt+2 > cq always

  f32x4 oacc[4], lacc;
#pragma unroll
  for (int t = 0; t < 4; ++t) oacc[t] = (f32x4){0.f, 0.f, 0.f, 0.f};
  lacc = (f32x4){0.f, 0.f, 0.f, 0.f};

  auto stage = [&](int bufi, int kc0) {
    int row = tid >> 3;
    int c = (tid & 7) * 8;
    int src = c ^ ((row & 7) * 8);
    gload_lds16(Kp + (size_t)(kc0 + row) * HD + src, &kS[bufi][tid * 8]);
    gload_lds16(Vt + (size_t)row * NN + kc0 + src, &vS[bufi][tid * 8]);
  };

  stage(0, 0);
  int buf = 0;
  size_t tilebase = (size_t)(qt * 8 + w) * 128;
  int sw = (r & 7) * 8;

  for (int ch = 0; ch < nch; ++ch) {
    int kc0 = ch * 64;
    __syncthreads();
    if (ch + 1 < nch) stage(buf ^ 1, kc0 + 64);

    uint2 ub[4];
#pragma unroll
    for (int st = 0; st < 4; ++st)
      ub[st] = *(const uint2*)&pbt[(tilebase + (kc0 >> 4) + st) * 256 + lane * 4];

    f32x4 sacc[4];
    __builtin_amdgcn_s_setprio(1);
#pragma unroll
    for (int st = 0; st < 4; ++st) {
      sacc[st] = (f32x4){0.f, 0.f, 0.f, 0.f};
      int rowb = (st * 16 + r) * 64;
      bf16x8 kf0 = *(const bf16x8*)&kS[buf][rowb + ((g * 8) ^ sw)];
      bf16x8 kf1 = *(const bf16x8*)&kS[buf][rowb + ((32 + g * 8) ^ sw)];
      sacc[st] = __builtin_amdgcn_mfma_f32_16x16x32_bf16(kf0, qf0, sacc[st], 0, 0, 0);
      sacc[st] = __builtin_amdgcn_mfma_f32_16x16x32_bf16(kf1, qf1, sacc[st], 0, 0, 0);
    }
    __builtin_amdgcn_s_setprio(0);

    // z = logit (log2 domain), packed pairs; no running max needed
    f32x2 z2[8];
    if (ch > cq) {
      float uu = fmaf(slope, (float)(kc0 - qbase), aL);
      f32x2 uu2 = {uu, uu};
#pragma unroll
      for (int st = 0; st < 4; ++st) {
        f32x2 pbl = {__uint_as_float(ub[st].x << 16), __uint_as_float(ub[st].x & 0xffff0000u)};
        f32x2 pbh = {__uint_as_float(ub[st].y << 16), __uint_as_float(ub[st].y & 0xffff0000u)};
        f32x2 s0 = {sacc[st][0], sacc[st][1]};
        f32x2 s1 = {sacc[st][2], sacc[st][3]};
        z2[st*2]   = s0 * C2 + pbl - (uu2 + sconst2[st*2]);
        z2[st*2+1] = s1 * C2 + pbh - (uu2 + sconst2[st*2+1]);
      }
    } else if (ch < cq) {
#pragma unroll
      for (int st = 0; st < 4; ++st) {
        f32x2 pbl = {__uint_as_float(ub[st].x << 16), __uint_as_float(ub[st].x & 0xffff0000u)};
        f32x2 pbh = {__uint_as_float(ub[st].y << 16), __uint_as_float(ub[st].y & 0xffff0000u)};
        f32x2 s0 = {sacc[st][0], sacc[st][1]};
        f32x2 s1 = {sacc[st][2], sacc[st][3]};
        z2[st*2]   = s0 * C2 + pbl;
        z2[st*2+1] = s1 * C2 + pbh;
      }
    } else {
      int kqb = kc0 + g * 4 - qbase - r;
#pragma unroll
      for (int st = 0; st < 4; ++st) {
        float p0 = __uint_as_float(ub[st].x << 16);
        float p1 = __uint_as_float(ub[st].x & 0xffff0000u);
        float p2 = __uint_as_float(ub[st].y << 16);
        float p3 = __uint_as_float(ub[st].y & 0xffff0000u);
        float pb4[4] = {p0, p1, p2, p3};
#pragma unroll
        for (int rr = 0; rr < 4; ++rr) {
          int dk = kqb + st * 16 + rr;
          float dist = (dk > 0) ? (float)dk : 0.f;
          z2[st*2 + (rr >> 1)][rr & 1] = fmaf(sacc[st][rr], C, pb4[rr]) - slope * dist;
        }
      }
    }

    // exp2 + pack straight into PV A-fragments (k-perm matches V's sigma layout)
    bf16x8 pa0, pa1;
#pragma unroll
    for (int j = 0; j < 8; ++j) {
      pa0[j] = (__bf16)exp2f(z2[j >> 1][j & 1]);
      pa1[j] = (__bf16)exp2f(z2[4 + (j >> 1)][j & 1]);
    }

    __builtin_amdgcn_s_setprio(1);
#pragma unroll
    for (int t = 0; t < 4; ++t) {
      int rowb = (t * 16 + r) * 64;
      bf16x8 vf0 = *(const bf16x8*)&vS[buf][rowb + ((g * 8) ^ sw)];
      bf16x8 vf1 = *(const bf16x8*)&vS[buf][rowb + ((32 + g * 8) ^ sw)];
      oacc[t] = __builtin_amdgcn_mfma_f32_16x16x32_bf16(pa0, vf0, oacc[t], 0, 0, 0);
      oacc[t] = __builtin_amdgcn_mfma_f32_16x16x32_bf16(pa1, vf1, oacc[t], 0, 0, 0);
    }
    lacc = __builtin_amdgcn_mfma_f32_16x16x32_bf16(pa0, onesf, lacc, 0, 0, 0);
    lacc = __builtin_amdgcn_mfma_f32_16x16x32_bf16(pa1, onesf, lacc, 0, 0, 0);
    __builtin_amdgcn_s_setprio(0);
    buf ^= 1;
  }

#pragma unroll
  for (int rr = 0; rr < 4; ++rr) {
    int qg = qbase + g * 4 + rr;
    float inv = 1.f / lacc[rr];
#pragma unroll
    for (int t = 0; t < 4; ++t) {
      float v = oacc[t][rr] * inv;
      ob[((size_t)(b * NN) + qg) * DD + h * HD + t * 16 + r] = (__bf16)v;
    }
  }
}

extern "C" void kernel_launch(void* const* d_in, const int* in_sizes, int n_in,
                              void* d_out, int out_size, void* d_ws, size_t ws_size,
                              hipStream_t stream) {
  const float* x    = (const float*)d_in[0];
  const float* pb   = (const float*)d_in[1];
  const float* alpha= (const float*)d_in[2];
  const float* dw7  = (const float*)d_in[3];
  const float* dw25 = (const float*)d_in[4];
  const float* dw49 = (const float*)d_in[5];
  const float* ln1g = (const float*)d_in[6];
  const float* ln1b = (const float*)d_in[7];
  const float* ln2g = (const float*)d_in[8];
  const float* ln2b = (const float*)d_in[9];
  const float* Wq   = (const float*)d_in[10];
  const float* bq   = (const float*)d_in[11];
  const float* Wk   = (const float*)d_in[12];
  const float* bk   = (const float*)d_in[13];
  const float* Wv   = (const float*)d_in[14];
  const float* bv   = (const float*)d_in[15];
  const float* Wo   = (const float*)d_in[16];
  const float* bo   = (const float*)d_in[17];
  const float* W1   = (const float*)d_in[18];
  const float* b1   = (const float*)d_in[19];
  const float* W2   = (const float*)d_in[20];
  const float* b2   = (const float*)d_in[21];
  const float* tw   = (const float*)d_in[22];
  const float* tb   = (const float*)d_in[23];
  float* out = (float*)d_out;

  char* w = (char*)d_ws;
  size_t off = 0;
  auto alloc = [&](size_t bytes) -> char* {
    char* p = w + off;
    off = (off + bytes + 255) & ~(size_t)255;
    return p;
  };
  float*  wc    = (float*)alloc(49 * 1024 * 4);
  float*  b3    = (float*)alloc(3072 * 4);
  __bf16* xs    = (__bf16*)alloc((size_t)MM * DD * 2);
  __bf16* Sb    = (__bf16*)alloc((size_t)MM * DD * 2);
  __bf16* toutb = (__bf16*)alloc((size_t)MM * DD * 2);
  __bf16* sn    = (__bf16*)alloc((size_t)MM * DD * 2);
  __bf16* qkv   = (__bf16*)alloc((size_t)3 * MM * DD * 2);
  __bf16* gb    = (__bf16*)alloc((size_t)MM * HID_ * 2);
  __bf16* wall  = (__bf16*)alloc((size_t)12582912 * 2);
  __bf16* pbt   = (__bf16*)alloc((size_t)NN * NN * 2);
  __bf16* wqkvb = wall;
  __bf16* wob   = wall + (size_t)3 * DD * DD;
  __bf16* w1b   = wall + (size_t)4 * DD * DD;
  __bf16* w2b   = wall + (size_t)4 * DD * DD + (size_t)HID_ * DD;
  __bf16* obuf  = sn;     // alias: sn dead after QKV gemm
  __bf16* hb    = qkv;    // alias: q dead after attention

  const size_t BHND = (size_t)BB * HH * NN * HD;

  k_wcomb<<<50, 256, 0, stream>>>(alpha, dw7, dw25, dw49, wc, bq, bk, bv, b3, out);
  k_cvtall<<<14336, 256, 0, stream>>>(Wq, Wk, Wv, Wo, W1, W2, pb, wall, pbt);
  k_decomp<<<1024, 256, 0, stream>>>(x, wc, tw, tb, Sb, toutb);
  k_ln<<<MM, 256, 0, stream>>>(Sb, ln1g, ln1b, sn);
  k_gemm<0,128,32><<<dim3(24, 32), 256, 0, stream>>>(sn, wqkvb, DD, b3, nullptr, nullptr, nullptr, qkv);
  k_attn<<<BB * HH * (NN / 128), 512, 0, stream>>>(qkv, qkv + BHND, qkv + 2 * BHND, pbt, obuf);
  k_gemm<1,64,64><<<dim3(16, 32), 256, 0, stream>>>(obuf, wob, DD, bo, Sb, nullptr, nullptr, xs);
  k_ln<<<MM, 256, 0, stream>>>(xs, ln2g, ln2b, hb);
  k_gemm<2,128,64><<<dim3(32, 32), 256, 0, stream>>>(hb, w1b, DD, b1, nullptr, nullptr, nullptr, gb);
  k_gemm<3,64,64><<<dim3(16, 32), 256, 0, stream>>>(gb, w2b, HID_, b2, xs, toutb, out, nullptr);
}

// Round 15
// 298.392 us; speedup vs baseline: 1.0058x; 1.0018x over previous
//
#include <hip/hip_runtime.h>
#include <cstdint>

#define BB 2
#define NN 2048
#define DD 1024
#define HH 16
#define HD 64
#define HID_ 4096
#define MM (BB*NN)

typedef __bf16 bf16x8 __attribute__((ext_vector_type(8)));
typedef __bf16 bf16x4 __attribute__((ext_vector_type(4)));
typedef float  f32x4  __attribute__((ext_vector_type(4)));
typedef float  f32x2  __attribute__((ext_vector_type(2)));

__device__ inline void gload_lds16(const void* g, void* l) {
  __builtin_amdgcn_global_load_lds((const __attribute__((address_space(1))) char*)g,
                                   (__attribute__((address_space(3))) char*)l, 16, 0, 0);
}

// ---------- prep: decomposition weights + qkv bias concat + out-tail ----------
__global__ void k_wcomb(const float* __restrict__ alpha, const float* __restrict__ dw7,
                        const float* __restrict__ dw25, const float* __restrict__ dw49,
                        float* __restrict__ wc,
                        const float* __restrict__ bq, const float* __restrict__ bk,
                        const float* __restrict__ bv, float* __restrict__ b3,
                        float* __restrict__ out) {
  int t = blockIdx.x;  // 0..48 decomp weights, 49 = bias concat + tail
  if (t == 49) {
    if (threadIdx.x == 0) out[(size_t)BB * NN * DD] = 0.f;  // scalar output 1
    for (int i = threadIdx.x; i < 3 * DD; i += blockDim.x) {
      const float* s = (i < DD) ? bq : (i < 2 * DD ? bk : bv);
      b3[i] = s[i & (DD - 1)];
    }
    return;
  }
  float a0 = alpha[0], a1 = alpha[1], a2 = alpha[2];
  float mx = fmaxf(a0, fmaxf(a1, a2));
  float e0 = __expf(a0 - mx), e1 = __expf(a1 - mx), e2 = __expf(a2 - mx);
  float inv = 1.f / (e0 + e1 + e2);
  float w0 = e0 * inv, w1 = e1 * inv, w2 = e2 * inv;
  for (int d = threadIdx.x; d < DD; d += blockDim.x) {
    float v = w2 * dw49[d * 49 + t];
    if (t >= 12 && t <= 36) v += w1 * dw25[d * 25 + (t - 12)];
    if (t >= 21 && t <= 27) v += w0 * dw7[d * 7 + (t - 21)];
    wc[t * DD + d] = v;
  }
}

// weight converts + pbt transform in ONE launch.
__global__ __launch_bounds__(256) void k_cvtall(const float* __restrict__ Wq, const float* __restrict__ Wk,
                         const float* __restrict__ Wv, const float* __restrict__ Wo,
                         const float* __restrict__ W1, const float* __restrict__ W2,
                         const float* __restrict__ pb,
                         __bf16* __restrict__ dst, __bf16* __restrict__ pbt) {
  int bid = blockIdx.x;
  if (bid >= 12288) {
    int q = bid - 12288;
    int qt16 = q >> 4, qm = q & 15;
    const float LOG2E = 1.4426950408889634f;
    for (int k4 = threadIdx.x; k4 < NN / 4; k4 += 256) {
      int k = k4 * 4;
      float4 v = *(const float4*)&pb[(size_t)q * NN + k];
      int kt = k >> 4, g = (k >> 2) & 3;
      bf16x4 o;
      o[0] = (__bf16)(v.x * LOG2E); o[1] = (__bf16)(v.y * LOG2E);
      o[2] = (__bf16)(v.z * LOG2E); o[3] = (__bf16)(v.w * LOG2E);
      *(bf16x4*)&pbt[((size_t)qt16 * 128 + kt) * 256 + (qm + 16 * g) * 4] = o;
    }
    return;
  }
  size_t i = ((size_t)bid * 256 + threadIdx.x) * 4;
  const float* s;
  if (i < 1048576u) s = Wq + i;
  else if (i < 2097152u) s = Wk + (i - 1048576u);
  else if (i < 3145728u) s = Wv + (i - 2097152u);
  else if (i < 4194304u) s = Wo + (i - 3145728u);
  else if (i < 8388608u) s = W1 + (i - 4194304u);
  else s = W2 + (i - 8388608u);
  float4 v = *(const float4*)s;
  dst[i] = (__bf16)v.x; dst[i+1] = (__bf16)v.y; dst[i+2] = (__bf16)v.z; dst[i+3] = (__bf16)v.w;
}

// ---------- fused series decomposition + trend conv (bf16 outputs) ----------
__global__ __launch_bounds__(256) void k_decomp(const float* __restrict__ x,
                                                const float* __restrict__ wc,
                                                const float* __restrict__ tw,
                                                const float* __restrict__ tb,
                                                __bf16* __restrict__ S,
                                                __bf16* __restrict__ tout) {
  int bid = blockIdx.x;
  int db = bid & 3, ns = (bid >> 2) & 127, b = bid >> 9;
  int d = db * 256 + threadIdx.x;
  int n0 = ns * 16;
  const float* xb = x + (size_t)b * NN * DD + d;
  float xw[68];
#pragma unroll
  for (int i = 0; i < 68; ++i) {
    int n = n0 - 26 + i;
    n = (n < 0) ? -n : n;
    n = (n > NN - 1) ? 2 * (NN - 1) - n : n;
    xw[i] = xb[(size_t)n * DD];
  }
  float Tx[20];
#pragma unroll
  for (int j = 0; j < 20; ++j) Tx[j] = 0.f;
#pragma unroll
  for (int t = 0; t < 49; ++t) {
    float wv = wc[t * DD + d];
#pragma unroll
    for (int j = 0; j < 20; ++j) Tx[j] = fmaf(wv, xw[j + t], Tx[j]);
  }
#pragma unroll
  for (int j = 0; j < 20; ++j) {
    int row = n0 - 2 + j;
    if (row < 0 || row >= NN) Tx[j] = 0.f;
  }
  float tw5[5];
#pragma unroll
  for (int t = 0; t < 5; ++t) tw5[t] = tw[d * 5 + t];
  float tbv = tb[d];
  size_t base = ((size_t)b * NN + n0) * DD + d;
#pragma unroll
  for (int i = 0; i < 16; ++i) {
    S[base + (size_t)i * DD] = (__bf16)(xw[i + 26] - Tx[i + 2]);
    float acc = tbv;
#pragma unroll
    for (int t = 0; t < 5; ++t) acc = fmaf(tw5[t], Tx[i + t], acc);
    tout[base + (size_t)i * DD] = (__bf16)acc;
  }
}

// ---------- LayerNorm (bf16 in -> bf16 out) ----------
__global__ __launch_bounds__(256) void k_ln(const __bf16* __restrict__ xv,
                                            const float* __restrict__ g,
                                            const float* __restrict__ bt,
                                            __bf16* __restrict__ y) {
  int row = blockIdx.x;
  int i = threadIdx.x * 4;
  bf16x4 x4 = *(const bf16x4*)(xv + (size_t)row * DD + i);
  float4 v;
  v.x = (float)x4[0]; v.y = (float)x4[1]; v.z = (float)x4[2]; v.w = (float)x4[3];
  float s = v.x + v.y + v.z + v.w;
  float sq = v.x * v.x + v.y * v.y + v.z * v.z + v.w * v.w;
#pragma unroll
  for (int m = 1; m <= 32; m <<= 1) { s += __shfl_xor(s, m); sq += __shfl_xor(sq, m); }
  __shared__ float rs[4], rq[4];
  int wid = threadIdx.x >> 6;
  if ((threadIdx.x & 63) == 0) { rs[wid] = s; rq[wid] = sq; }
  __syncthreads();
  s = rs[0] + rs[1] + rs[2] + rs[3];
  sq = rq[0] + rq[1] + rq[2] + rq[3];
  float mean = s * (1.f / DD);
  float var = sq * (1.f / DD) - mean * mean;
  float rstd = rsqrtf(var + 1e-5f);
  float4 gv = *(const float4*)&g[i];
  float4 bv = *(const float4*)&bt[i];
  __bf16* yr = y + (size_t)row * DD + i;
  yr[0] = (__bf16)((v.x - mean) * rstd * gv.x + bv.x);
  yr[1] = (__bf16)((v.y - mean) * rstd * gv.y + bv.y);
  yr[2] = (__bf16)((v.z - mean) * rstd * gv.z + bv.z);
  yr[3] = (__bf16)((v.w - mean) * rstd * gv.w + bv.w);
}

// ---------- GEMM: C[M,N] = A[M,K] * Bw[N,K]^T, tile 128 x BNT, K-step BKT ----------
template <int EPI, int BNT, int BKT>
__global__ __launch_bounds__(256) void k_gemm(const __bf16* __restrict__ A,
                                              const __bf16* __restrict__ Bw, int K,
                                              const float* __restrict__ bias,
                                              const __bf16* __restrict__ auxb1,
                                              const __bf16* __restrict__ auxb2,
                                              float* __restrict__ outf,
                                              __bf16* __restrict__ outb) {
  constexpr int NFR = BNT / 32;
  constexpr int NKK = BKT / 32;
  __shared__ __bf16 aS[2][128 * BKT];
  __shared__ __bf16 bS[2][BNT * BKT];
  const int tid = threadIdx.x;
  const int lane = tid & 63;
  const int wid = tid >> 6;
  const int wm = wid >> 1, wn = wid & 1;
  const int r = lane & 15, gq = lane >> 4;
  const int gx = gridDim.x;
  const int G = gx * gridDim.y;
  int bid = blockIdx.y * gx + blockIdx.x;
  int swz = (bid & 7) * (G >> 3) + (bid >> 3);
  const int m0 = (swz / gx) * 128;
  const int n0 = (swz % gx) * BNT;
  const int rsw = (BKT == 64) ? (r & 7) * 8 : 0;

  f32x4 acc[4][NFR];
#pragma unroll
  for (int mi = 0; mi < 4; ++mi)
#pragma unroll
    for (int ni = 0; ni < NFR; ++ni) acc[mi][ni] = (f32x4){0.f, 0.f, 0.f, 0.f};

  auto stage = [&](int bufi, int k0) {
#pragma unroll
    for (int i = 0; i < (128 * BKT) / 2048; ++i) {
      int e = i * 2048 + tid * 8;
      int row = e / BKT, col = e % BKT;
      int src = (BKT == 64) ? (col ^ ((row & 7) * 8)) : col;
      gload_lds16(A + (size_t)(m0 + row) * K + k0 + src, &aS[bufi][e]);
    }
#pragma unroll
    for (int i = 0; i < (BNT * BKT) / 2048; ++i) {
      int e = i * 2048 + tid * 8;
      int row = e / BKT, col = e % BKT;
      int src = (BKT == 64) ? (col ^ ((row & 7) * 8)) : col;
      gload_lds16(Bw + (size_t)(n0 + row) * K + k0 + src, &bS[bufi][e]);
    }
  };

  stage(0, 0);
  const int nk = K / BKT;
  int buf = 0;
  for (int kt = 0; kt < nk; ++kt) {
    __syncthreads();
    if (kt + 1 < nk) stage(buf ^ 1, (kt + 1) * BKT);
    bf16x8 af[4][NKK], bfr[NFR][NKK];
#pragma unroll
    for (int mi = 0; mi < 4; ++mi)
#pragma unroll
      for (int kk = 0; kk < NKK; ++kk)
        af[mi][kk] = *reinterpret_cast<const bf16x8*>(
            &aS[buf][(wm * 64 + mi * 16 + r) * BKT + ((kk * 32 + gq * 8) ^ rsw)]);
#pragma unroll
    for (int ni = 0; ni < NFR; ++ni)
#pragma unroll
      for (int kk = 0; kk < NKK; ++kk)
        bfr[ni][kk] = *reinterpret_cast<const bf16x8*>(
            &bS[buf][(wn * (BNT / 2) + ni * 16 + r) * BKT + ((kk * 32 + gq * 8) ^ rsw)]);
    __builtin_amdgcn_s_setprio(1);
#pragma unroll
    for (int kk = 0; kk < NKK; ++kk)
#pragma unroll
      for (int mi = 0; mi < 4; ++mi)
#pragma unroll
        for (int ni = 0; ni < NFR; ++ni)
          acc[mi][ni] = __builtin_amdgcn_mfma_f32_16x16x32_bf16(af[mi][kk], bfr[ni][kk], acc[mi][ni], 0, 0, 0);
    __builtin_amdgcn_s_setprio(0);
    buf ^= 1;
  }

#pragma unroll
  for (int mi = 0; mi < 4; ++mi) {
#pragma unroll
    for (int ni = 0; ni < NFR; ++ni) {
      int colg = n0 + wn * (BNT / 2) + ni * 16 + r;
      float bcol = bias[colg];
#pragma unroll
      for (int rr = 0; rr < 4; ++rr) {
        int mg = m0 + wm * 64 + mi * 16 + gq * 4 + rr;
        float val = acc[mi][ni][rr] + bcol;
        if constexpr (EPI == 0) {
          int which = colg >> 10, e = colg & 1023;
          int hh = e >> 6, d = e & 63;
          int b = mg >> 11, nq = mg & (NN - 1);
          if (which == 2) {
            int nl = nq & 63, kk = nl & 31;
            int slot = ((kk >> 4) << 2) | (((kk >> 2) & 3) << 3) | (kk & 3) | (nl & 32);
            int nqp = (nq & ~63) | slot;
            outb[(size_t)2 * (BB * HH * NN * HD) +
                 ((size_t)((b * HH + hh) * HD + d)) * NN + nqp] = (__bf16)val;
          } else {
            outb[(size_t)which * (BB * HH * NN * HD) +
                 ((size_t)(b * HH + hh) * NN + nq) * HD + d] = (__bf16)val;
          }
        } else if constexpr (EPI == 1) {
          size_t idx = (size_t)mg * DD + colg;
          outb[idx] = (__bf16)((float)auxb1[idx] + val);
        } else if constexpr (EPI == 2) {
          float gl = val * 0.5f * (1.f + erff(val * 0.70710678118f));
          outb[(size_t)mg * HID_ + colg] = (__bf16)gl;
        } else {
          size_t idx = (size_t)mg * DD + colg;
          outf[idx] = val + (float)auxb1[idx] + (float)auxb2[idx];
        }
      }
    }
  }
}

// ---------- flash attention: truncated chunks + balanced complementary pairing ----------
// 512 blocks = 512 residency slots: all co-resident, so makespan = max over CUs of
// the SUM of the 2 co-resident blocks' work. Assume XCD slot s and s+32 share a CU:
// slot s<32 takes work-rank j=s*8+x (descending work), s>=32 takes 511-j
// -> pairs (j, 511-j), pair sums ~uniform (~53 chunk-iters).
__global__ __launch_bounds__(512) void k_attn(const __bf16* __restrict__ qb,
                                              const __bf16* __restrict__ kb,
                                              const __bf16* __restrict__ vtb,
                                              const __bf16* __restrict__ pbt,
                                              __bf16* __restrict__ ob) {
  __shared__ __bf16 kS[2][64 * 64];
  __shared__ __bf16 vS[2][64 * 64];
  int i = blockIdx.x;
  int x = i & 7;                 // XCD (round-robin on dispatch index)
  int s = i >> 3;                // slot within XCD, 0..63
  int j = (s < 32) ? (s * 8 + x) : (511 - ((s - 32) * 8 + x));  // work rank, 0=longest
  int h = 15 - (j >> 5);         // rank-major: h descending
  int r32 = j & 31;
  int qt = 15 - (r32 >> 1);      // within h: qt descending (work grows with qt)
  int b = r32 & 1;
  int bh = b * HH + h;
  int tid = threadIdx.x;
  int lane = tid & 63, w = tid >> 6;
  int r = lane & 15, g = lane >> 4;
  const __bf16* Kp = kb + (size_t)bh * NN * HD;
  const __bf16* Vt = vtb + (size_t)bh * HD * NN;
  int qbase = qt * 128 + w * 16;
  int cq = qt * 2 + (w >> 2);
  const __bf16* Q = qb + ((size_t)bh * NN + qbase) * HD;

  bf16x8 qf0 = *(const bf16x8*)&Q[(size_t)r * HD + g * 8];
  bf16x8 qf1 = *(const bf16x8*)&Q[(size_t)r * HD + 32 + g * 8];
  bf16x8 onesf;
#pragma unroll
  for (int jj = 0; jj < 8; ++jj) onesf[jj] = (__bf16)1.0f;

  const float C = 0.18033688011112042f;          // 0.125 * log2(e)
  const f32x2 C2 = {C, C};
  float slope = exp2f(-0.5f * (float)(h + 1)) * 1.4426950408889634f;  // log2/token
  f32x2 sconst2[8];
#pragma unroll
  for (int st = 0; st < 4; ++st) {
    sconst2[st * 2]     = (f32x2){slope * (float)(st * 16),     slope * (float)(st * 16 + 1)};
    sconst2[st * 2 + 1] = (f32x2){slope * (float)(st * 16 + 2), slope * (float)(st * 16 + 3)};
  }
  float aL = slope * (float)(g * 4 - r);

  // truncation: last chunk with any token within 64 log2-units of suppression
  int qmaxb = qt * 128 + 127;
  int lastch = (int)floorf(((float)qmaxb + 64.0f / slope) * (1.0f / 64.0f));
  int nch = min(NN / 64, lastch + 1);   // nch >= 2*qt+2 > cq always

  f32x4 oacc[4], lacc;
#pragma unroll
  for (int t = 0; t < 4; ++t) oacc[t] = (f32x4){0.f, 0.f, 0.f, 0.f};
  lacc = (f32x4){0.f, 0.f, 0.f, 0.f};

  auto stage = [&](int bufi, int kc0) {
    int row = tid >> 3;
    int c = (tid & 7) * 8;
    int src = c ^ ((row & 7) * 8);
    gload_lds16(Kp + (size_t)(kc0 + row) * HD + src, &kS[bufi][tid * 8]);
    gload_lds16(Vt + (size_t)row * NN + kc0 + src, &vS[bufi][tid * 8]);
  };

  stage(0, 0);
  int buf = 0;
  size_t tilebase = (size_t)(qt * 8 + w) * 128;
  int sw = (r & 7) * 8;

  for (int ch = 0; ch < nch; ++ch) {
    int kc0 = ch * 64;
    __syncthreads();
    if (ch + 1 < nch) stage(buf ^ 1, kc0 + 64);

    uint2 ub[4];
#pragma unroll
    for (int st = 0; st < 4; ++st)
      ub[st] = *(const uint2*)&pbt[(tilebase + (kc0 >> 4) + st) * 256 + lane * 4];

    f32x4 sacc[4];
    __builtin_amdgcn_s_setprio(1);
#pragma unroll
    for (int st = 0; st < 4; ++st) {
      sacc[st] = (f32x4){0.f, 0.f, 0.f, 0.f};
      int rowb = (st * 16 + r) * 64;
      bf16x8 kf0 = *(const bf16x8*)&kS[buf][rowb + ((g * 8) ^ sw)];
      bf16x8 kf1 = *(const bf16x8*)&kS[buf][rowb + ((32 + g * 8) ^ sw)];
      sacc[st] = __builtin_amdgcn_mfma_f32_16x16x32_bf16(kf0, qf0, sacc[st], 0, 0, 0);
      sacc[st] = __builtin_amdgcn_mfma_f32_16x16x32_bf16(kf1, qf1, sacc[st], 0, 0, 0);
    }
    __builtin_amdgcn_s_setprio(0);

    // z = logit (log2 domain), packed pairs; no running max needed
    f32x2 z2[8];
    if (ch > cq) {
      float uu = fmaf(slope, (float)(kc0 - qbase), aL);
      f32x2 uu2 = {uu, uu};
#pragma unroll
      for (int st = 0; st < 4; ++st) {
        f32x2 pbl = {__uint_as_float(ub[st].x << 16), __uint_as_float(ub[st].x & 0xffff0000u)};
        f32x2 pbh = {__uint_as_float(ub[st].y << 16), __uint_as_float(ub[st].y & 0xffff0000u)};
        f32x2 s0 = {sacc[st][0], sacc[st][1]};
        f32x2 s1 = {sacc[st][2], sacc[st][3]};
        z2[st*2]   = s0 * C2 + pbl - (uu2 + sconst2[st*2]);
        z2[st*2+1] = s1 * C2 + pbh - (uu2 + sconst2[st*2+1]);
      }
    } else if (ch < cq) {
#pragma unroll
      for (int st = 0; st < 4; ++st) {
        f32x2 pbl = {__uint_as_float(ub[st].x << 16), __uint_as_float(ub[st].x & 0xffff0000u)};
        f32x2 pbh = {__uint_as_float(ub[st].y << 16), __uint_as_float(ub[st].y & 0xffff0000u)};
        f32x2 s0 = {sacc[st][0], sacc[st][1]};
        f32x2 s1 = {sacc[st][2], sacc[st][3]};
        z2[st*2]   = s0 * C2 + pbl;
        z2[st*2+1] = s1 * C2 + pbh;
      }
    } else {
      int kqb = kc0 + g * 4 - qbase - r;
#pragma unroll
      for (int st = 0; st < 4; ++st) {
        float p0 = __uint_as_float(ub[st].x << 16);
        float p1 = __uint_as_float(ub[st].x & 0xffff0000u);
        float p2 = __uint_as_float(ub[st].y << 16);
        float p3 = __uint_as_float(ub[st].y & 0xffff0000u);
        float pb4[4] = {p0, p1, p2, p3};
#pragma unroll
        for (int rr = 0; rr < 4; ++rr) {
          int dk = kqb + st * 16 + rr;
          float dist = (dk > 0) ? (float)dk : 0.f;
          z2[st*2 + (rr >> 1)][rr & 1] = fmaf(sacc[st][rr], C, pb4[rr]) - slope * dist;
        }
      }
    }

    // exp2 + pack straight into PV A-fragments (k-perm matches V's sigma layout)
    bf16x8 pa0, pa1;
#pragma unroll
    for (int jj = 0; jj < 8; ++jj) {
      pa0[jj] = (__bf16)exp2f(z2[jj >> 1][jj & 1]);
      pa1[jj] = (__bf16)exp2f(z2[4 + (jj >> 1)][jj & 1]);
    }

    __builtin_amdgcn_s_setprio(1);
#pragma unroll
    for (int t = 0; t < 4; ++t) {
      int rowb = (t * 16 + r) * 64;
      bf16x8 vf0 = *(const bf16x8*)&vS[buf][rowb + ((g * 8) ^ sw)];
      bf16x8 vf1 = *(const bf16x8*)&vS[buf][rowb + ((32 + g * 8) ^ sw)];
      oacc[t] = __builtin_amdgcn_mfma_f32_16x16x32_bf16(pa0, vf0, oacc[t], 0, 0, 0);
      oacc[t] = __builtin_amdgcn_mfma_f32_16x16x32_bf16(pa1, vf1, oacc[t], 0, 0, 0);
    }
    lacc = __builtin_amdgcn_mfma_f32_16x16x32_bf16(pa0, onesf, lacc, 0, 0, 0);
    lacc = __builtin_amdgcn_mfma_f32_16x16x32_bf16(pa1, onesf, lacc, 0, 0, 0);
    __builtin_amdgcn_s_setprio(0);
    buf ^= 1;
  }

#pragma unroll
  for (int rr = 0; rr < 4; ++rr) {
    int qg = qbase + g * 4 + rr;
    float inv = 1.f / lacc[rr];
#pragma unroll
    for (int t = 0; t < 4; ++t) {
      float v = oacc[t][rr] * inv;
      ob[((size_t)(b * NN) + qg) * DD + h * HD + t * 16 + r] = (__bf16)v;
    }
  }
}

extern "C" void kernel_launch(void* const* d_in, const int* in_sizes, int n_in,
                              void* d_out, int out_size, void* d_ws, size_t ws_size,
                              hipStream_t stream) {
  const float* x    = (const float*)d_in[0];
  const float* pb   = (const float*)d_in[1];
  const float* alpha= (const float*)d_in[2];
  const float* dw7  = (const float*)d_in[3];
  const float* dw25 = (const float*)d_in[4];
  const float* dw49 = (const float*)d_in[5];
  const float* ln1g = (const float*)d_in[6];
  const float* ln1b = (const float*)d_in[7];
  const float* ln2g = (const float*)d_in[8];
  const float* ln2b = (const float*)d_in[9];
  const float* Wq   = (const float*)d_in[10];
  const float* bq   = (const float*)d_in[11];
  const float* Wk   = (const float*)d_in[12];
  const float* bk   = (const float*)d_in[13];
  const float* Wv   = (const float*)d_in[14];
  const float* bv   = (const float*)d_in[15];
  const float* Wo   = (const float*)d_in[16];
  const float* bo   = (const float*)d_in[17];
  const float* W1   = (const float*)d_in[18];
  const float* b1   = (const float*)d_in[19];
  const float* W2   = (const float*)d_in[20];
  const float* b2   = (const float*)d_in[21];
  const float* tw   = (const float*)d_in[22];
  const float* tb   = (const float*)d_in[23];
  float* out = (float*)d_out;

  char* w = (char*)d_ws;
  size_t off = 0;
  auto alloc = [&](size_t bytes) -> char* {
    char* p = w + off;
    off = (off + bytes + 255) & ~(size_t)255;
    return p;
  };
  float*  wc    = (float*)alloc(49 * 1024 * 4);
  float*  b3    = (float*)alloc(3072 * 4);
  __bf16* xs    = (__bf16*)alloc((size_t)MM * DD * 2);
  __bf16* Sb    = (__bf16*)alloc((size_t)MM * DD * 2);
  __bf16* toutb = (__bf16*)alloc((size_t)MM * DD * 2);
  __bf16* sn    = (__bf16*)alloc((size_t)MM * DD * 2);
  __bf16* qkv   = (__bf16*)alloc((size_t)3 * MM * DD * 2);
  __bf16* gb    = (__bf16*)alloc((size_t)MM * HID_ * 2);
  __bf16* wall  = (__bf16*)alloc((size_t)12582912 * 2);
  __bf16* pbt   = (__bf16*)alloc((size_t)NN * NN * 2);
  __bf16* wqkvb = wall;
  __bf16* wob   = wall + (size_t)3 * DD * DD;
  __bf16* w1b   = wall + (size_t)4 * DD * DD;
  __bf16* w2b   = wall + (size_t)4 * DD * DD + (size_t)HID_ * DD;
  __bf16* obuf  = sn;     // alias: sn dead after QKV gemm
  __bf16* hb    = qkv;    // alias: q dead after attention

  const size_t BHND = (size_t)BB * HH * NN * HD;

  k_wcomb<<<50, 256, 0, stream>>>(alpha, dw7, dw25, dw49, wc, bq, bk, bv, b3, out);
  k_cvtall<<<14336, 256, 0, stream>>>(Wq, Wk, Wv, Wo, W1, W2, pb, wall, pbt);
  k_decomp<<<1024, 256, 0, stream>>>(x, wc, tw, tb, Sb, toutb);
  k_ln<<<MM, 256, 0, stream>>>(Sb, ln1g, ln1b, sn);
  k_gemm<0,128,32><<<dim3(24, 32), 256, 0, stream>>>(sn, wqkvb, DD, b3, nullptr, nullptr, nullptr, qkv);
  k_attn<<<BB * HH * (NN / 128), 512, 0, stream>>>(qkv, qkv + BHND, qkv + 2 * BHND, pbt, obuf);
  k_gemm<1,64,64><<<dim3(16, 32), 256, 0, stream>>>(obuf, wob, DD, bo, Sb, nullptr, nullptr, xs);
  k_ln<<<MM, 256, 0, stream>>>(xs, ln2g, ln2b, hb);
  k_gemm<2,128,64><<<dim3(32, 32), 256, 0, stream>>>(hb, w1b, DD, b1, nullptr, nullptr, nullptr, gb);
  k_gemm<3,64,64><<<dim3(16, 32), 256, 0, stream>>>(gb, w2b, HID_, b2, xs, toutb, out, nullptr);
}